// Round 1
// baseline (176.413 us; speedup 1.0000x reference)
//
#include <hip/hip_runtime.h>
#include <hip/hip_bf16.h>

// Problem constants (from reference): B=2048, D=3, K=64, H=768, N=4096
#define BATCH 2048
#define DEPTH 3
#define FANOUT 64
#define HID 768
#define NTHREADS 256

// One block per sample b. 4 waves/block; each wave handles 16 of the 64
// fanout rows per depth. Per k-row: coalesced float4 sweep over H=768
// (64 lanes * 4 floats * 3 iters), then 64-lane shuffle reduce.
__global__ __launch_bounds__(NTHREADS) void hier_head_kernel(
    const float* __restrict__ pooled,   // [B, H]
    const int*   __restrict__ nodes,    // [B, D]
    const int*   __restrict__ path,     // [B, D]
    const float* __restrict__ W,        // [N, K, H]
    const float* __restrict__ bias,     // [N, K]
    float* __restrict__ losses,         // [B]
    float* __restrict__ logits_out)     // [B, D, K]
{
    const int b    = blockIdx.x;
    const int tid  = threadIdx.x;
    const int wave = tid >> 6;
    const int lane = tid & 63;

    __shared__ float s_pooled[HID];
    __shared__ float s_logits[DEPTH * FANOUT];

    // Stage pooled[b] into LDS (768 floats = 192 float4 loads)
    const float4* p4 = reinterpret_cast<const float4*>(pooled + (size_t)b * HID);
    for (int i = tid; i < HID / 4; i += NTHREADS) {
        reinterpret_cast<float4*>(s_pooled)[i] = p4[i];
    }
    __syncthreads();

    // Each lane caches its 12 pooled values (h = 4*lane + 256*it + {0..3})
    float pr[12];
#pragma unroll
    for (int it = 0; it < 3; ++it) {
        float4 v = reinterpret_cast<float4*>(s_pooled)[lane + 64 * it];
        pr[it * 4 + 0] = v.x;
        pr[it * 4 + 1] = v.y;
        pr[it * 4 + 2] = v.z;
        pr[it * 4 + 3] = v.w;
    }

    for (int d = 0; d < DEPTH; ++d) {
        const int n = nodes[b * DEPTH + d];
        const float* Wn = W + (size_t)n * FANOUT * HID;
        const int kbase = wave * 16;
#pragma unroll 4
        for (int kk = 0; kk < 16; ++kk) {
            const int k = kbase + kk;
            const float4* w4 = reinterpret_cast<const float4*>(Wn + (size_t)k * HID);
            float acc = 0.f;
#pragma unroll
            for (int it = 0; it < 3; ++it) {
                float4 v = w4[lane + 64 * it];
                acc += v.x * pr[it * 4 + 0] + v.y * pr[it * 4 + 1] +
                       v.z * pr[it * 4 + 2] + v.w * pr[it * 4 + 3];
            }
            // 64-lane butterfly reduce
#pragma unroll
            for (int off = 32; off > 0; off >>= 1)
                acc += __shfl_xor(acc, off, 64);
            if (lane == 0)
                s_logits[d * FANOUT + k] = acc + bias[(size_t)n * FANOUT + k];
        }
    }
    __syncthreads();

    // Write logits out: D*K = 192 floats
    float* lg_out = logits_out + (size_t)b * DEPTH * FANOUT;
    if (tid < DEPTH * FANOUT) lg_out[tid] = s_logits[tid];

    // Loss: wave 0 only. lane l holds logits[d][l]; shuffle max + sum-exp.
    if (wave == 0) {
        float loss = 0.f;
        for (int d = 0; d < DEPTH; ++d) {
            float x = s_logits[d * FANOUT + lane];
            float m = x;
#pragma unroll
            for (int off = 32; off > 0; off >>= 1)
                m = fmaxf(m, __shfl_xor(m, off, 64));
            float e = expf(x - m);
#pragma unroll
            for (int off = 32; off > 0; off >>= 1)
                e += __shfl_xor(e, off, 64);
            const float lse = m + logf(e);
            const int t = path[b * DEPTH + d];
            loss += lse - s_logits[d * FANOUT + t];
        }
        if (lane == 0) losses[b] = loss;
    }
}

extern "C" void kernel_launch(void* const* d_in, const int* in_sizes, int n_in,
                              void* d_out, int out_size, void* d_ws, size_t ws_size,
                              hipStream_t stream) {
    const float* pooled = (const float*)d_in[0];  // [B, H]
    const int*   nodes  = (const int*)d_in[1];    // [B, D]
    const int*   path   = (const int*)d_in[2];    // [B, D]
    const float* W      = (const float*)d_in[3];  // [N, K, H]
    const float* bias   = (const float*)d_in[4];  // [N, K]

    float* losses = (float*)d_out;                // [B]
    float* logits = (float*)d_out + BATCH;        // [B, D, K]

    hipLaunchKernelGGL(hier_head_kernel, dim3(BATCH), dim3(NTHREADS), 0, stream,
                       pooled, nodes, path, W, bias, losses, logits);
}

// Round 2
// 141.879 us; speedup vs baseline: 1.2434x; 1.2434x over previous
//
#include <hip/hip_runtime.h>
#include <hip/hip_bf16.h>

// Problem constants: B=2048, D=3, K=64, H=768, N=4096
#define BATCH   2048
#define DEPTH   3
#define FANOUT  64
#define HID     768
#define NNODES  4096
#define NPAIRS  (BATCH * DEPTH)   // 6144
#define CAP     8                 // per-node list capacity (P[Poisson(1.5)>8] ~ 4e-4)

// ---- ws layout (in ints) ----
// count  [0,            4096)
// ocnt   [4096,         4112)   (only [4096] used; padded)
// list   [4112,         4112 + 4096*8)
// ovfl   [36880,        36880 + 6144)
#define WS_COUNT 0
#define WS_OCNT  4096
#define WS_LIST  4112
#define WS_OVFL  (4112 + NNODES * CAP)   // 36880
#define WS_ZERO_INTS 4112                // zero counts + ocnt each call

__global__ __launch_bounds__(256) void zero_ws_kernel(int* ws) {
    int i = blockIdx.x * 256 + threadIdx.x;
    if (i < WS_ZERO_INTS) ws[i] = 0;
}

// Bin (b,d) pairs by node id. Order within a list is non-deterministic but
// results are order-invariant (each pair's logits computed independently).
__global__ __launch_bounds__(256) void bin_kernel(const int* __restrict__ nodes,
                                                  int* __restrict__ ws) {
    int idx = blockIdx.x * 256 + threadIdx.x;
    if (idx >= NPAIRS) return;
    int n = nodes[idx];
    int pos = atomicAdd(&ws[WS_COUNT + n], 1);
    if (pos < CAP) {
        ws[WS_LIST + n * CAP + pos] = idx;
    } else {
        int op = atomicAdd(&ws[WS_OCNT], 1);
        ws[WS_OVFL + op] = idx;
    }
}

// One block per node: read W[n] ONCE, apply to all (<=CAP) samples mapped to it.
__global__ __launch_bounds__(256) void node_gemm_kernel(
    const float* __restrict__ pooled,   // [B, H]
    const float* __restrict__ W,        // [N, K, H]
    const float* __restrict__ bias,     // [N, K]
    const int*   __restrict__ ws,
    float*       __restrict__ logits)   // [B, D, K]
{
    const int n = blockIdx.x;
    int c = ws[WS_COUNT + n];
    if (c == 0) return;
    c = min(c, CAP);

    __shared__ float s_pool[CAP][HID];
    __shared__ float s_log[CAP][FANOUT];
    __shared__ int   s_pair[CAP];

    const int tid  = threadIdx.x;
    const int wave = tid >> 6;
    const int lane = tid & 63;

    if (tid < c) s_pair[tid] = ws[WS_LIST + n * CAP + tid];
    __syncthreads();

    // Stage the c pooled vectors into LDS (coalesced float4)
    for (int idx = tid; idx < c * (HID / 4); idx += 256) {
        int s = idx / (HID / 4);
        int f = idx % (HID / 4);
        int b = s_pair[s] / DEPTH;
        reinterpret_cast<float4*>(&s_pool[s][0])[f] =
            reinterpret_cast<const float4*>(pooled + (size_t)b * HID)[f];
    }
    __syncthreads();

    const float* Wn = W + (size_t)n * FANOUT * HID;
#pragma unroll 2
    for (int kk = 0; kk < 16; ++kk) {
        const int k = wave * 16 + kk;
        const float4* w4 = reinterpret_cast<const float4*>(Wn + (size_t)k * HID);
        float4 w0 = w4[lane], w1 = w4[lane + 64], w2 = w4[lane + 128];
        for (int s = 0; s < c; ++s) {
            const float4* p4 = reinterpret_cast<const float4*>(&s_pool[s][0]);
            float4 a0 = p4[lane], a1 = p4[lane + 64], a2 = p4[lane + 128];
            float acc = w0.x * a0.x + w0.y * a0.y + w0.z * a0.z + w0.w * a0.w
                      + w1.x * a1.x + w1.y * a1.y + w1.z * a1.z + w1.w * a1.w
                      + w2.x * a2.x + w2.y * a2.y + w2.z * a2.z + w2.w * a2.w;
#pragma unroll
            for (int off = 32; off > 0; off >>= 1)
                acc += __shfl_xor(acc, off, 64);
            if (lane == 0) s_log[s][k] = acc;
        }
    }
    __syncthreads();

    // Coalesced write-out with bias
    for (int idx = tid; idx < c * FANOUT; idx += 256) {
        int s = idx >> 6, k = idx & 63;
        int pair = s_pair[s];
        int b = pair / DEPTH, d = pair % DEPTH;
        logits[((size_t)b * DEPTH + d) * FANOUT + k] =
            s_log[s][k] + bias[(size_t)n * FANOUT + k];
    }
}

// Fallback: pairs that overflowed a node's CAP slots (expected ~0).
// One wave per overflow pair, full 64-row gemv.
__global__ __launch_bounds__(256) void overflow_kernel(
    const float* __restrict__ pooled,
    const float* __restrict__ W,
    const float* __restrict__ bias,
    const int*   __restrict__ ws,
    float*       __restrict__ logits)
{
    const int oc = ws[WS_OCNT];
    if (oc <= 0) return;
    const int lane = threadIdx.x & 63;
    const int gw   = (blockIdx.x * blockDim.x + threadIdx.x) >> 6;
    const int nw   = (gridDim.x * blockDim.x) >> 6;

    for (int i = gw; i < oc; i += nw) {
        int pair = ws[WS_OVFL + i];
        int b = pair / DEPTH, d = pair % DEPTH;
        // node id: re-derive from nodes is not passed; overflow pairs only exist
        // when count>CAP, so read node from the count structure is impossible —
        // instead the pair index maps back through the nodes array via ws? No:
        // we stored the pair index; fetch node from global nodes array below.
        // (nodes pointer passed via 'bias'-adjacent param list — see launch.)
        int n = ((const int*)ws)[0]; // placeholder overwritten below
        (void)n;
        // NOTE: actual node id loaded from g_nodes (passed separately)
        i = i; // no-op
        break;
    }
}

// Correct overflow kernel (with nodes pointer)
__global__ __launch_bounds__(256) void overflow_kernel2(
    const float* __restrict__ pooled,
    const float* __restrict__ W,
    const float* __restrict__ bias,
    const int*   __restrict__ nodes,
    const int*   __restrict__ ws,
    float*       __restrict__ logits)
{
    const int oc = ws[WS_OCNT];
    if (oc <= 0) return;
    const int lane = threadIdx.x & 63;
    const int gw   = (blockIdx.x * blockDim.x + threadIdx.x) >> 6;
    const int nw   = (gridDim.x * blockDim.x) >> 6;

    for (int i = gw; i < oc; i += nw) {
        int pair = ws[WS_OVFL + i];
        int b = pair / DEPTH, d = pair % DEPTH;
        int n = nodes[pair];
        const float4* p4 = reinterpret_cast<const float4*>(pooled + (size_t)b * HID);
        float4 a0 = p4[lane], a1 = p4[lane + 64], a2 = p4[lane + 128];
        const float* Wn = W + (size_t)n * FANOUT * HID;
        for (int k = 0; k < FANOUT; ++k) {
            const float4* w4 = reinterpret_cast<const float4*>(Wn + (size_t)k * HID);
            float4 w0 = w4[lane], w1 = w4[lane + 64], w2 = w4[lane + 128];
            float acc = w0.x * a0.x + w0.y * a0.y + w0.z * a0.z + w0.w * a0.w
                      + w1.x * a1.x + w1.y * a1.y + w1.z * a1.z + w1.w * a1.w
                      + w2.x * a2.x + w2.y * a2.y + w2.z * a2.z + w2.w * a2.w;
#pragma unroll
            for (int off = 32; off > 0; off >>= 1)
                acc += __shfl_xor(acc, off, 64);
            if (lane == 0)
                logits[((size_t)b * DEPTH + d) * FANOUT + k] =
                    acc + bias[(size_t)n * FANOUT + k];
        }
    }
}

// Per-sample CE loss from the logits buffer. One wave per sample, lane = k.
__global__ __launch_bounds__(256) void loss_kernel(
    const float* __restrict__ logits,   // [B, D, K]
    const int*   __restrict__ path,     // [B, D]
    float*       __restrict__ losses)   // [B]
{
    const int wave = threadIdx.x >> 6;
    const int lane = threadIdx.x & 63;
    const int b = blockIdx.x * 4 + wave;
    if (b >= BATCH) return;
    const float* lg = logits + (size_t)b * DEPTH * FANOUT;
    float loss = 0.f;
#pragma unroll
    for (int d = 0; d < DEPTH; ++d) {
        float x = lg[d * FANOUT + lane];
        float m = x;
#pragma unroll
        for (int off = 32; off > 0; off >>= 1)
            m = fmaxf(m, __shfl_xor(m, off, 64));
        float e = expf(x - m);
#pragma unroll
        for (int off = 32; off > 0; off >>= 1)
            e += __shfl_xor(e, off, 64);
        float lse = m + logf(e);
        int t = path[b * DEPTH + d];
        loss += lse - __shfl(x, t, 64);
    }
    if (lane == 0) losses[b] = loss;
}

extern "C" void kernel_launch(void* const* d_in, const int* in_sizes, int n_in,
                              void* d_out, int out_size, void* d_ws, size_t ws_size,
                              hipStream_t stream) {
    const float* pooled = (const float*)d_in[0];  // [B, H]
    const int*   nodes  = (const int*)d_in[1];    // [B, D]
    const int*   path   = (const int*)d_in[2];    // [B, D]
    const float* W      = (const float*)d_in[3];  // [N, K, H]
    const float* bias   = (const float*)d_in[4];  // [N, K]

    float* losses = (float*)d_out;                // [B]
    float* logits = (float*)d_out + BATCH;        // [B, D, K]
    int*   ws     = (int*)d_ws;

    hipLaunchKernelGGL(zero_ws_kernel, dim3((WS_ZERO_INTS + 255) / 256), dim3(256),
                       0, stream, ws);
    hipLaunchKernelGGL(bin_kernel, dim3((NPAIRS + 255) / 256), dim3(256),
                       0, stream, nodes, ws);
    hipLaunchKernelGGL(node_gemm_kernel, dim3(NNODES), dim3(256),
                       0, stream, pooled, W, bias, ws, logits);
    hipLaunchKernelGGL(overflow_kernel2, dim3(16), dim3(256),
                       0, stream, pooled, W, bias, nodes, ws, logits);
    hipLaunchKernelGGL(loss_kernel, dim3((BATCH + 3) / 4), dim3(256),
                       0, stream, logits, path, losses);
}